// Round 1
// baseline (139.995 us; speedup 1.0000x reference)
//
#include <hip/hip_runtime.h>
#include <hip/hip_bf16.h>
#include <stdint.h>

#define NROWS 8192
#define DIM   256
#define TILE  128
#define BK    32

typedef __attribute__((ext_vector_type(8))) short short8;
typedef __attribute__((ext_vector_type(4))) float floatx4;

typedef const __attribute__((address_space(1))) uint32_t gas_u32;
typedef __attribute__((address_space(3))) uint32_t las_u32;

__device__ __forceinline__ void gload_lds16(const void* g, void* l) {
    // lands at (uniform lds base) + lane*16 ; per-lane global address
    __builtin_amdgcn_global_load_lds((gas_u32*)(uintptr_t)g,
                                     (las_u32*)(uintptr_t)l, 16, 0, 0);
}

__device__ __forceinline__ unsigned short f2bf(float x) {
    __hip_bfloat16 h = __float2bfloat16(x);
    unsigned short u;
    __builtin_memcpy(&u, &h, 2);
    return u;
}

// ------------- Kernel 1: row-normalize fp32 -> bf16 (one wave per row) -------------
__global__ __launch_bounds__(256) void normalize_kernel(const float* __restrict__ emb,
                                                        uint16_t* __restrict__ ebf)
{
    int row  = blockIdx.x * 4 + (threadIdx.x >> 6);
    int lane = threadIdx.x & 63;
    const float4* rowp = (const float4*)(emb + (size_t)row * DIM);
    float4 v = rowp[lane];
    float ss = v.x*v.x + v.y*v.y + v.z*v.z + v.w*v.w;
    #pragma unroll
    for (int off = 32; off > 0; off >>= 1)
        ss += __shfl_xor(ss, off, 64);
    float norm = sqrtf(ss);
    float inv  = 1.0f / fmaxf(norm, 1e-8f);
    ushort4 h;
    h.x = f2bf(v.x * inv);
    h.y = f2bf(v.y * inv);
    h.z = f2bf(v.z * inv);
    h.w = f2bf(v.w * inv);
    *(ushort4*)(ebf + (size_t)row * DIM + lane * 4) = h;
}

// ------------- Kernel 2: 128x128 sim tile + fused exp/mask/row-reduce -------------
// grid (64, 64): bi = i-tile, bj = j-tile. Writes per-(jtile,row) partial sums.
__global__ __launch_bounds__(256) void tile_kernel(const uint16_t* __restrict__ ebf,
                                                   const int* __restrict__ tgt,
                                                   float* __restrict__ ppos,
                                                   float* __restrict__ pneg)
{
    __shared__ uint16_t sA[TILE * BK];   // 8 KB, xor-swizzled chunk layout
    __shared__ uint16_t sB[TILE * BK];   // 8 KB
    __shared__ float rsp[2][TILE];
    __shared__ float rsn[2][TILE];
    __shared__ int   sTi[TILE];
    __shared__ int   sTj[TILE];

    const int bi   = blockIdx.x;
    const int bj   = blockIdx.y;
    const int tid  = threadIdx.x;
    const int wave = tid >> 6;
    const int lane = tid & 63;
    const int quad = lane >> 4;
    const int m    = lane & 15;

    if (tid < TILE) {
        sTi[tid] = tgt[bi * TILE + tid];
        sTj[tid] = tgt[bj * TILE + tid];
    }

    floatx4 acc[4][4];
    #pragma unroll
    for (int a = 0; a < 4; ++a)
        #pragma unroll
        for (int b = 0; b < 4; ++b)
            acc[a][b] = (floatx4){0.f, 0.f, 0.f, 0.f};

    const int wr = (wave >> 1) * 64;   // wave row base within tile
    const int wc = (wave & 1) * 64;    // wave col base within tile

    // staging map: phys 16B chunk p holds global chunk (row = p>>2, logical lc = (p&3)^(row&3))
    int aoff[2];
    #pragma unroll
    for (int t = 0; t < 2; ++t) {
        int p   = wave * 128 + t * 64 + lane;
        int row = p >> 2;
        int lc  = (p & 3) ^ (row & 3);
        aoff[t] = row * (DIM * 2) + lc * 16;   // byte offset within tile rows (kc = 0)
    }

    const char* gA = (const char*)(ebf + (size_t)bi * TILE * DIM);
    const char* gB = (const char*)(ebf + (size_t)bj * TILE * DIM);
    char* lA = (char*)sA;
    char* lB = (char*)sB;

    const int swz = (quad ^ (m & 3)) * 16;  // swizzled chunk select for fragment reads

    for (int kc = 0; kc < DIM / BK; ++kc) {
        #pragma unroll
        for (int t = 0; t < 2; ++t) {
            gload_lds16(gA + aoff[t] + kc * 64, lA + wave * 2048 + t * 1024);
            gload_lds16(gB + aoff[t] + kc * 64, lB + wave * 2048 + t * 1024);
        }
        __syncthreads();   // drains vmcnt -> staged data visible

        short8 af[4], bf[4];
        #pragma unroll
        for (int tr = 0; tr < 4; ++tr)
            af[tr] = *(const short8*)(lA + (wr + tr * 16 + m) * 64 + swz);
        #pragma unroll
        for (int tc = 0; tc < 4; ++tc)
            bf[tc] = *(const short8*)(lB + (wc + tc * 16 + m) * 64 + swz);

        #pragma unroll
        for (int tr = 0; tr < 4; ++tr)
            #pragma unroll
            for (int tc = 0; tc < 4; ++tc)
                acc[tr][tc] = __builtin_amdgcn_mfma_f32_16x16x32_bf16(
                    af[tr], bf[tc], acc[tr][tc], 0, 0, 0);
        __syncthreads();   // all reads done before restage
    }

    // ---- epilogue: exp(sim-10), pos/neg masked row sums ----
    int tj[4];
    #pragma unroll
    for (int tc = 0; tc < 4; ++tc) tj[tc] = sTj[wc + tc * 16 + m];

    #pragma unroll
    for (int tr = 0; tr < 4; ++tr) {
        const int rowloc = wr + tr * 16 + quad * 4;   // + r
        int ti[4];
        #pragma unroll
        for (int r = 0; r < 4; ++r) ti[r] = sTi[rowloc + r];
        float ps[4] = {0.f, 0.f, 0.f, 0.f};
        float ns[4] = {0.f, 0.f, 0.f, 0.f};
        #pragma unroll
        for (int tc = 0; tc < 4; ++tc) {
            const int jglob = bj * TILE + wc + tc * 16 + m;
            const int tjv = tj[tc];
            #pragma unroll
            for (int r = 0; r < 4; ++r) {
                float v = __expf(fmaf(10.f, acc[tr][tc][r], -10.f));
                const int iglob = bi * TILE + rowloc + r;
                if (iglob == jglob) v = 0.f;          // exclude diagonal everywhere
                const bool pos = (ti[r] == tjv);
                ps[r] += pos ? v : 0.f;
                ns[r] += pos ? 0.f : v;
            }
        }
        #pragma unroll
        for (int r = 0; r < 4; ++r) {
            #pragma unroll
            for (int off = 1; off < 16; off <<= 1) {
                ps[r] += __shfl_xor(ps[r], off, 64);
                ns[r] += __shfl_xor(ns[r], off, 64);
            }
            if (m == 0) {
                rsp[wave & 1][rowloc + r] = ps[r];
                rsn[wave & 1][rowloc + r] = ns[r];
            }
        }
    }
    __syncthreads();

    if (tid < TILE) {
        size_t idx = (size_t)bj * NROWS + (size_t)bi * TILE + tid;
        ppos[idx] = rsp[0][tid] + rsp[1][tid];
        pneg[idx] = rsn[0][tid] + rsn[1][tid];
    }
}

// ------------- Kernel 3: per-row log-diff + global sum -------------
__global__ __launch_bounds__(256) void finalize_kernel(const float* __restrict__ ppos,
                                                       const float* __restrict__ pneg,
                                                       float* __restrict__ out)
{
    const int i = blockIdx.x * 256 + threadIdx.x;
    float sp = 0.f, sn = 0.f;
    #pragma unroll 8
    for (int jt = 0; jt < NROWS / TILE; ++jt) {
        sp += ppos[(size_t)jt * NROWS + i];
        sn += pneg[(size_t)jt * NROWS + i];
    }
    float loss = logf(sn) - logf(sp);   // the fixed +10 shifts cancel
    #pragma unroll
    for (int off = 32; off > 0; off >>= 1)
        loss += __shfl_xor(loss, off, 64);
    __shared__ float w4[4];
    if ((threadIdx.x & 63) == 0) w4[threadIdx.x >> 6] = loss;
    __syncthreads();
    if (threadIdx.x == 0)
        atomicAdd(out, w4[0] + w4[1] + w4[2] + w4[3]);
}

extern "C" void kernel_launch(void* const* d_in, const int* in_sizes, int n_in,
                              void* d_out, int out_size, void* d_ws, size_t ws_size,
                              hipStream_t stream)
{
    (void)in_sizes; (void)n_in; (void)out_size; (void)ws_size;
    const float* emb = (const float*)d_in[0];
    const int*   tgt = (const int*)d_in[1];
    float*       out = (float*)d_out;

    uint16_t* ebf  = (uint16_t*)d_ws;                                   // 4 MB
    float*    ppos = (float*)((char*)d_ws + (size_t)NROWS * DIM * 2);   // 2 MB
    float*    pneg = ppos + (size_t)(NROWS / TILE) * NROWS;             // 2 MB

    hipMemsetAsync(d_out, 0, sizeof(float), stream);

    normalize_kernel<<<NROWS / 4, 256, 0, stream>>>(emb, ebf);

    dim3 grid(NROWS / TILE, NROWS / TILE);
    tile_kernel<<<grid, 256, 0, stream>>>(ebf, tgt, ppos, pneg);

    finalize_kernel<<<NROWS / 256, 256, 0, stream>>>(ppos, pneg, out);
}

// Round 2
// 115.318 us; speedup vs baseline: 1.2140x; 1.2140x over previous
//
#include <hip/hip_runtime.h>
#include <hip/hip_bf16.h>
#include <stdint.h>

#define NROWS 8192
#define DIM   256
#define BJ    256          // A-operand (j) rows per block
#define BI    128          // B-operand (i) rows per block
#define BK    32
#define NJT   (NROWS/BJ)   // 32
#define NIT   (NROWS/BI)   // 64

typedef __attribute__((ext_vector_type(8))) short short8;
typedef __attribute__((ext_vector_type(4))) float floatx4;

typedef const __attribute__((address_space(1))) uint32_t gas_u32;
typedef __attribute__((address_space(3))) uint32_t las_u32;

__device__ __forceinline__ void gload_lds16(const void* g, void* l) {
    // LDS dest = wave-uniform base + lane*16 ; global src per-lane
    __builtin_amdgcn_global_load_lds((gas_u32*)(uintptr_t)g,
                                     (las_u32*)(uintptr_t)l, 16, 0, 0);
}

__device__ __forceinline__ unsigned short f2bf(float x) {
    __hip_bfloat16 h = __float2bfloat16(x);
    unsigned short u;
    __builtin_memcpy(&u, &h, 2);
    return u;
}

// ------------- Kernel 1: row-normalize fp32 -> bf16 (one wave per row) -------------
__global__ __launch_bounds__(256) void normalize_kernel(const float* __restrict__ emb,
                                                        uint16_t* __restrict__ ebf)
{
    int row  = blockIdx.x * 4 + (threadIdx.x >> 6);
    int lane = threadIdx.x & 63;
    const float4* rowp = (const float4*)(emb + (size_t)row * DIM);
    float4 v = rowp[lane];
    float ss = v.x*v.x + v.y*v.y + v.z*v.z + v.w*v.w;
    #pragma unroll
    for (int off = 32; off > 0; off >>= 1)
        ss += __shfl_xor(ss, off, 64);
    float inv = 1.0f / fmaxf(sqrtf(ss), 1e-8f);
    ushort4 h;
    h.x = f2bf(v.x * inv);
    h.y = f2bf(v.y * inv);
    h.z = f2bf(v.z * inv);
    h.w = f2bf(v.w * inv);
    *(ushort4*)(ebf + (size_t)row * DIM + lane * 4) = h;
}

// ------------- Kernel 2: 256j x 128i sim tile, fused exp/mask, in-register i-sums -------
// C[row=j][col=i]: each lane owns fixed i per tc, accumulates its 16 j's in register.
// grid (NIT, NJT). Writes per-(jtile, i) partial sums.
__global__ __launch_bounds__(256, 2) void tile_kernel(const uint16_t* __restrict__ ebf,
                                                      const int* __restrict__ tgt,
                                                      float* __restrict__ ppos,
                                                      float* __restrict__ pneg)
{
    __shared__ uint16_t sA[BJ * BK];   // 16 KB, xor-swizzled chunk layout (j rows)
    __shared__ uint16_t sB[BI * BK];   //  8 KB (i rows)
    __shared__ float rsp[2][BI];
    __shared__ float rsn[2][BI];
    __shared__ int   sTi[BI];
    __shared__ int   sTj[BJ];

    const int bi   = blockIdx.x;
    const int bj   = blockIdx.y;
    const int tid  = threadIdx.x;
    const int wave = tid >> 6;
    const int lane = tid & 63;
    const int quad = lane >> 4;
    const int m    = lane & 15;

    if (tid < BI) sTi[tid] = tgt[bi * BI + tid];
    sTj[tid] = tgt[bj * BJ + tid];

    floatx4 acc[8][4];
    #pragma unroll
    for (int a = 0; a < 8; ++a)
        #pragma unroll
        for (int b = 0; b < 4; ++b)
            acc[a][b] = (floatx4){0.f, 0.f, 0.f, 0.f};

    const int wr = (wave >> 1) * 128;  // wave j base
    const int wc = (wave & 1) * 64;    // wave i base

    // staging: phys 16B chunk p -> row = p>>2, logical chunk lc = (p&3)^(row&3)
    int aoffA[4];
    #pragma unroll
    for (int t = 0; t < 4; ++t) {
        int p   = wave * 256 + t * 64 + lane;
        int row = p >> 2;
        int lc  = (p & 3) ^ (row & 3);
        aoffA[t] = row * (DIM * 2) + lc * 16;
    }
    int aoffB[2];
    #pragma unroll
    for (int t = 0; t < 2; ++t) {
        int q   = wave * 128 + t * 64 + lane;
        int row = q >> 2;
        int lc  = (q & 3) ^ (row & 3);
        aoffB[t] = row * (DIM * 2) + lc * 16;
    }

    const char* gA = (const char*)(ebf + (size_t)bj * BJ * DIM);  // j rows
    const char* gB = (const char*)(ebf + (size_t)bi * BI * DIM);  // i rows
    char* lA = (char*)sA;
    char* lB = (char*)sB;

    const int swz = (quad ^ (m & 3)) * 16;  // swizzled chunk select on read

    for (int kc = 0; kc < DIM / BK; ++kc) {
        #pragma unroll
        for (int t = 0; t < 4; ++t)
            gload_lds16(gA + aoffA[t] + kc * 64, lA + wave * 4096 + t * 1024);
        #pragma unroll
        for (int t = 0; t < 2; ++t)
            gload_lds16(gB + aoffB[t] + kc * 64, lB + wave * 2048 + t * 1024);
        __syncthreads();   // drains vmcnt -> staged data visible

        short8 af[8], bfr[4];
        #pragma unroll
        for (int tj = 0; tj < 8; ++tj)
            af[tj] = *(const short8*)(lA + (wr + tj * 16 + m) * 64 + swz);
        #pragma unroll
        for (int tc = 0; tc < 4; ++tc)
            bfr[tc] = *(const short8*)(lB + (wc + tc * 16 + m) * 64 + swz);

        #pragma unroll
        for (int tj = 0; tj < 8; ++tj)
            #pragma unroll
            for (int tc = 0; tc < 4; ++tc)
                acc[tj][tc] = __builtin_amdgcn_mfma_f32_16x16x32_bf16(
                    af[tj], bfr[tc], acc[tj][tc], 0, 0, 0);
        __syncthreads();   // reads done before restage
    }

    // ---- epilogue: exp(sim-10), pos/neg sums per fixed i, in-register over j ----
    int ti4[4];
    #pragma unroll
    for (int tc = 0; tc < 4; ++tc) ti4[tc] = sTi[wc + tc * 16 + m];

    float ps[4] = {0.f, 0.f, 0.f, 0.f};
    float ns[4] = {0.f, 0.f, 0.f, 0.f};

    #pragma unroll
    for (int tj = 0; tj < 8; ++tj) {
        const int jl = wr + tj * 16 + (quad << 2);
        const int jglob = bj * BJ + jl;
        int tjv[4];
        #pragma unroll
        for (int r = 0; r < 4; ++r) tjv[r] = sTj[jl + r];
        #pragma unroll
        for (int tc = 0; tc < 4; ++tc) {
            const int iglob = bi * BI + wc + tc * 16 + m;
            const int tiv = ti4[tc];
            #pragma unroll
            for (int r = 0; r < 4; ++r) {
                float v = __expf(fmaf(10.f, acc[tj][tc][r], -10.f));
                if (jglob + r == iglob) v = 0.f;      // exclude diagonal everywhere
                const bool pos = (tjv[r] == tiv);
                ps[tc] += pos ? v : 0.f;
                ns[tc] += pos ? 0.f : v;
            }
        }
    }

    // quad-reduction (the only cross-lane step): lanes m,m+16,m+32,m+48 hold
    // disjoint j's for the same i
    #pragma unroll
    for (int tc = 0; tc < 4; ++tc) {
        ps[tc] += __shfl_xor(ps[tc], 16, 64);
        ps[tc] += __shfl_xor(ps[tc], 32, 64);
        ns[tc] += __shfl_xor(ns[tc], 16, 64);
        ns[tc] += __shfl_xor(ns[tc], 32, 64);
    }
    if (quad == 0) {
        #pragma unroll
        for (int tc = 0; tc < 4; ++tc) {
            rsp[wave >> 1][wc + tc * 16 + m] = ps[tc];
            rsn[wave >> 1][wc + tc * 16 + m] = ns[tc];
        }
    }
    __syncthreads();

    if (tid < BI) {
        size_t idx = (size_t)bj * NROWS + (size_t)bi * BI + tid;
        ppos[idx] = rsp[0][tid] + rsp[1][tid];
        pneg[idx] = rsn[0][tid] + rsn[1][tid];
    }
}

// ------------- Kernel 3: per-row log-diff + global sum -------------
__global__ __launch_bounds__(256) void finalize_kernel(const float* __restrict__ ppos,
                                                       const float* __restrict__ pneg,
                                                       float* __restrict__ out)
{
    const int i = blockIdx.x * 256 + threadIdx.x;
    float sp = 0.f, sn = 0.f;
    #pragma unroll 8
    for (int jt = 0; jt < NJT; ++jt) {
        sp += ppos[(size_t)jt * NROWS + i];
        sn += pneg[(size_t)jt * NROWS + i];
    }
    float loss = logf(sn) - logf(sp);   // fixed +10 shifts cancel
    #pragma unroll
    for (int off = 32; off > 0; off >>= 1)
        loss += __shfl_xor(loss, off, 64);
    __shared__ float w4[4];
    if ((threadIdx.x & 63) == 0) w4[threadIdx.x >> 6] = loss;
    __syncthreads();
    if (threadIdx.x == 0)
        atomicAdd(out, w4[0] + w4[1] + w4[2] + w4[3]);
}

extern "C" void kernel_launch(void* const* d_in, const int* in_sizes, int n_in,
                              void* d_out, int out_size, void* d_ws, size_t ws_size,
                              hipStream_t stream)
{
    (void)in_sizes; (void)n_in; (void)out_size; (void)ws_size;
    const float* emb = (const float*)d_in[0];
    const int*   tgt = (const int*)d_in[1];
    float*       out = (float*)d_out;

    uint16_t* ebf  = (uint16_t*)d_ws;                                   // 4 MB
    float*    ppos = (float*)((char*)d_ws + (size_t)NROWS * DIM * 2);   // 1 MB
    float*    pneg = ppos + (size_t)NJT * NROWS;                        // 1 MB

    hipMemsetAsync(d_out, 0, sizeof(float), stream);

    normalize_kernel<<<NROWS / 4, 256, 0, stream>>>(emb, ebf);

    dim3 grid(NIT, NJT);
    tile_kernel<<<grid, 256, 0, stream>>>(ebf, tgt, ppos, pneg);

    finalize_kernel<<<NROWS / 256, 256, 0, stream>>>(ppos, pneg, out);
}

// Round 3
// 99.483 us; speedup vs baseline: 1.4072x; 1.1592x over previous
//
#include <hip/hip_runtime.h>
#include <hip/hip_bf16.h>
#include <stdint.h>

#define NROWS 8192
#define DIM   256          // elements per row; fp8 -> 256 B per row
#define BJ    256          // j rows per block (A operand)
#define BI    128          // i rows per block (B operand)
#define KCB   128          // K-bytes staged per chunk
#define NKC   2            // 256 B / 128 B
#define NJT   (NROWS/BJ)   // 32
#define NIT   (NROWS/BI)   // 64

typedef __attribute__((ext_vector_type(4))) int   int4v;
typedef __attribute__((ext_vector_type(8))) int   int8v;
typedef __attribute__((ext_vector_type(4))) float floatx4;

typedef const __attribute__((address_space(1))) uint32_t gas_u32;
typedef __attribute__((address_space(3))) uint32_t las_u32;

#define SCALE_1_16 0x7B7B7B7B   // E8M0 123 = 2^-4 in every byte (opsel-proof)

__device__ __forceinline__ void gload_lds16(const void* g, void* l) {
    // LDS dest = wave-uniform base + lane*16 ; global src per-lane
    __builtin_amdgcn_global_load_lds((gas_u32*)(uintptr_t)g,
                                     (las_u32*)(uintptr_t)l, 16, 0, 0);
}

// ------------- Kernel 1: row-normalize fp32 -> fp8 e4m3 (x16), one wave/row -------------
__global__ __launch_bounds__(256) void normalize_kernel(const float* __restrict__ emb,
                                                        uint32_t* __restrict__ e8)
{
    int row  = blockIdx.x * 4 + (threadIdx.x >> 6);
    int lane = threadIdx.x & 63;
    const float4* rowp = (const float4*)(emb + (size_t)row * DIM);
    float4 v = rowp[lane];
    float ss = v.x*v.x + v.y*v.y + v.z*v.z + v.w*v.w;
    #pragma unroll
    for (int off = 32; off > 0; off >>= 1)
        ss += __shfl_xor(ss, off, 64);
    // store e * 16 in e4m3; the MFMA scale (2^-4 per operand) removes the 2^8
    float inv = 16.0f / fmaxf(sqrtf(ss), 1e-8f);
    int r = __builtin_amdgcn_cvt_pk_fp8_f32(v.x * inv, v.y * inv, 0, false);
    r     = __builtin_amdgcn_cvt_pk_fp8_f32(v.z * inv, v.w * inv, r, true);
    e8[(size_t)row * (DIM / 4) + lane] = (uint32_t)r;
}

// ------------- Kernel 2: 256j x 128i tile, MX-fp8 K=128 MFMA, fused epilogue -------------
// C[row=j][col=i]: lane owns fixed i per tc, accumulates its j's in register.
__global__ __launch_bounds__(256, 2) void tile_kernel(const uint8_t* __restrict__ e8,
                                                      const int* __restrict__ tgt,
                                                      float* __restrict__ ppos,
                                                      float* __restrict__ pneg)
{
    __shared__ uint8_t sA[BJ * KCB];   // 32 KB (j rows, one 128B k-chunk, xor-swizzled 16B units)
    __shared__ uint8_t sB[BI * KCB];   // 16 KB (i rows)
    __shared__ float rsp[2][BI];
    __shared__ float rsn[2][BI];
    __shared__ int   sTi[BI];
    __shared__ int   sTj[BJ];

    const int bi   = blockIdx.x;
    const int bj   = blockIdx.y;
    const int tid  = threadIdx.x;
    const int wave = tid >> 6;
    const int lane = tid & 63;
    const int quad = lane >> 4;
    const int m    = lane & 15;

    if (tid < BI) sTi[tid] = tgt[bi * BI + tid];
    sTj[tid] = tgt[bj * BJ + tid];

    floatx4 acc[8][4];
    #pragma unroll
    for (int a = 0; a < 8; ++a)
        #pragma unroll
        for (int b = 0; b < 4; ++b)
            acc[a][b] = (floatx4){0.f, 0.f, 0.f, 0.f};

    const int wr = (wave >> 1) * 128;  // wave j base
    const int wc = (wave & 1) * 64;    // wave i base

    // staging: 16B slot s (linear in LDS) -> row = s>>3, phys chunk = s&7,
    // logical chunk lc = (s&7) ^ (row&7); global byte = row*256 + lc*16 (+ kc*128)
    int goffA[8];
    #pragma unroll
    for (int t = 0; t < 8; ++t) {
        int s   = wave * 512 + t * 64 + lane;
        int row = s >> 3;
        int lc  = (s & 7) ^ (row & 7);
        goffA[t] = row * 256 + lc * 16;
    }
    int goffB[4];
    #pragma unroll
    for (int t = 0; t < 4; ++t) {
        int s   = wave * 256 + t * 64 + lane;
        int row = s >> 3;
        int lc  = (s & 7) ^ (row & 7);
        goffB[t] = row * 256 + lc * 16;
    }

    const char* gA = (const char*)(e8 + (size_t)bj * BJ * 256);  // j rows
    const char* gB = (const char*)(e8 + (size_t)bi * BI * 256);  // i rows

    // fragment read: row&7 == m&7 (16 | tj*16 is 0 mod 8) -> xor is tj-independent
    const int xr = m & 7;
    const int c0 = (((quad << 1)    ) ^ xr) << 4;  // phys byte off of logical chunk 2q
    const int c1 = (((quad << 1) | 1) ^ xr) << 4;  // logical chunk 2q+1

    for (int kc = 0; kc < NKC; ++kc) {
        #pragma unroll
        for (int t = 0; t < 8; ++t)
            gload_lds16(gA + goffA[t] + kc * KCB, sA + wave * 8192 + t * 1024);
        #pragma unroll
        for (int t = 0; t < 4; ++t)
            gload_lds16(gB + goffB[t] + kc * KCB, sB + wave * 4096 + t * 1024);
        __syncthreads();   // drains vmcnt -> staged data visible

        int8v bfr[4];
        #pragma unroll
        for (int tc = 0; tc < 4; ++tc) {
            const uint8_t* pb = sB + (wc + tc * 16 + m) * KCB;
            int4v lo = *(const int4v*)(pb + c0);
            int4v hi = *(const int4v*)(pb + c1);
            bfr[tc] = __builtin_shufflevector(lo, hi, 0, 1, 2, 3, 4, 5, 6, 7);
        }
        #pragma unroll
        for (int tj = 0; tj < 8; ++tj) {
            const uint8_t* pa = sA + (wr + tj * 16 + m) * KCB;
            int4v lo = *(const int4v*)(pa + c0);
            int4v hi = *(const int4v*)(pa + c1);
            int8v af = __builtin_shufflevector(lo, hi, 0, 1, 2, 3, 4, 5, 6, 7);
            #pragma unroll
            for (int tc = 0; tc < 4; ++tc)
                acc[tj][tc] = __builtin_amdgcn_mfma_scale_f32_16x16x128_f8f6f4(
                    af, bfr[tc], acc[tj][tc], 0, 0,
                    0, SCALE_1_16, 0, SCALE_1_16);
        }
        __syncthreads();   // reads done before restage
    }

    // ---- epilogue: exp(sim-10), pos/neg sums per fixed i, in-register over j ----
    int ti4[4];
    #pragma unroll
    for (int tc = 0; tc < 4; ++tc) ti4[tc] = sTi[wc + tc * 16 + m];

    float ps[4] = {0.f, 0.f, 0.f, 0.f};
    float ns[4] = {0.f, 0.f, 0.f, 0.f};

    #pragma unroll
    for (int tj = 0; tj < 8; ++tj) {
        const int jl = wr + tj * 16 + (quad << 2);
        const int jglob = bj * BJ + jl;
        int tjv[4];
        #pragma unroll
        for (int r = 0; r < 4; ++r) tjv[r] = sTj[jl + r];
        #pragma unroll
        for (int tc = 0; tc < 4; ++tc) {
            const int iglob = bi * BI + wc + tc * 16 + m;
            const int tiv = ti4[tc];
            #pragma unroll
            for (int r = 0; r < 4; ++r) {
                float v = __expf(fmaf(10.f, acc[tj][tc][r], -10.f));
                if (jglob + r == iglob) v = 0.f;      // exclude diagonal everywhere
                const bool pos = (tjv[r] == tiv);
                ps[tc] += pos ? v : 0.f;
                ns[tc] += pos ? 0.f : v;
            }
        }
    }

    // quad-reduction: lanes m, m+16, m+32, m+48 hold disjoint j's for same i
    #pragma unroll
    for (int tc = 0; tc < 4; ++tc) {
        ps[tc] += __shfl_xor(ps[tc], 16, 64);
        ps[tc] += __shfl_xor(ps[tc], 32, 64);
        ns[tc] += __shfl_xor(ns[tc], 16, 64);
        ns[tc] += __shfl_xor(ns[tc], 32, 64);
    }
    if (quad == 0) {
        #pragma unroll
        for (int tc = 0; tc < 4; ++tc) {
            rsp[wave >> 1][wc + tc * 16 + m] = ps[tc];
            rsn[wave >> 1][wc + tc * 16 + m] = ns[tc];
        }
    }
    __syncthreads();

    if (tid < BI) {
        size_t idx = (size_t)bj * NROWS + (size_t)bi * BI + tid;
        ppos[idx] = rsp[0][tid] + rsp[1][tid];
        pneg[idx] = rsn[0][tid] + rsn[1][tid];
    }
}

// ------------- Kernel 3: per-row log-diff + global sum -------------
__global__ __launch_bounds__(256) void finalize_kernel(const float* __restrict__ ppos,
                                                       const float* __restrict__ pneg,
                                                       float* __restrict__ out)
{
    const int i = blockIdx.x * 256 + threadIdx.x;
    float sp = 0.f, sn = 0.f;
    #pragma unroll 8
    for (int jt = 0; jt < NJT; ++jt) {
        sp += ppos[(size_t)jt * NROWS + i];
        sn += pneg[(size_t)jt * NROWS + i];
    }
    float loss = logf(sn) - logf(sp);   // fixed +10 shifts cancel
    #pragma unroll
    for (int off = 32; off > 0; off >>= 1)
        loss += __shfl_xor(loss, off, 64);
    __shared__ float w4[4];
    if ((threadIdx.x & 63) == 0) w4[threadIdx.x >> 6] = loss;
    __syncthreads();
    if (threadIdx.x == 0)
        atomicAdd(out, w4[0] + w4[1] + w4[2] + w4[3]);
}

extern "C" void kernel_launch(void* const* d_in, const int* in_sizes, int n_in,
                              void* d_out, int out_size, void* d_ws, size_t ws_size,
                              hipStream_t stream)
{
    (void)in_sizes; (void)n_in; (void)out_size; (void)ws_size;
    const float* emb = (const float*)d_in[0];
    const int*   tgt = (const int*)d_in[1];
    float*       out = (float*)d_out;

    uint32_t* e8   = (uint32_t*)d_ws;                                    // 2 MB fp8 rows
    float*    ppos = (float*)((char*)d_ws + (size_t)NROWS * 256);        // 1 MB
    float*    pneg = ppos + (size_t)NJT * NROWS;                         // 1 MB

    hipMemsetAsync(d_out, 0, sizeof(float), stream);

    normalize_kernel<<<NROWS / 4, 256, 0, stream>>>(emb, e8);

    dim3 grid(NIT, NJT);
    tile_kernel<<<grid, 256, 0, stream>>>((const uint8_t*)e8, tgt, ppos, pneg);

    finalize_kernel<<<NROWS / 256, 256, 0, stream>>>(ppos, pneg, out);
}